// Round 6
// baseline (310.947 us; speedup 1.0000x reference)
//
#include <hip/hip_runtime.h>
#include <hip/hip_bf16.h>
#include <cmath>

// Problem constants
#define B_SZ 8
#define L_SZ 2048
#define D_SZ 1024
#define CH 341
#define CP 384               // padded channel dim (4 x 96)
#define LCONV 2046           // L - KERNEL + 1
#define NSEG 512
#define KDIM 3072            // 3 * 1024 folded conv K
#define NFCAP 256            // max fixup positions (expected ~10)

#define POOLED_N (B_SZ * NSEG * D_SZ)

typedef _Float16 f16x8 __attribute__((ext_vector_type(8)));
typedef float f32x4 __attribute__((ext_vector_type(4)));

__device__ __forceinline__ void gl_lds16(const void* g, void* l) {
    __builtin_amdgcn_global_load_lds(
        (const __attribute__((address_space(1))) unsigned int*)g,
        (__attribute__((address_space(3))) unsigned int*)l, 16, 0, 0);
}

// ---------------------------------------------------------------------------
// Convert hidden fp32 -> fp16; also zero h (6.3M floats), pooled (4.2M
// floats -- NOT 16.8M, that was the round-5 OOB crash), scalars, nf.
// Grid 8192 x 256 (one f16x8 per thread).
// ---------------------------------------------------------------------------
__global__ __launch_bounds__(256) void convert_hidden_kernel(
        const float* __restrict__ hidden, _Float16* __restrict__ hid16,
        float* __restrict__ h, float* __restrict__ pooled,
        float* __restrict__ out_scalars, int* __restrict__ nf) {
    size_t t = (size_t)blockIdx.x * 256 + threadIdx.x;   // < 2,097,152
    float4 v0 = ((const float4*)hidden)[t * 2];
    float4 v1 = ((const float4*)hidden)[t * 2 + 1];
    f16x8 o;
    o[0] = (_Float16)v0.x; o[1] = (_Float16)v0.y;
    o[2] = (_Float16)v0.z; o[3] = (_Float16)v0.w;
    o[4] = (_Float16)v1.x; o[5] = (_Float16)v1.y;
    o[6] = (_Float16)v1.z; o[7] = (_Float16)v1.w;
    ((f16x8*)hid16)[t] = o;
    const float4 z = make_float4(0.f, 0.f, 0.f, 0.f);
    if (t < (size_t)B_SZ * L_SZ * CP / 4)       // h: 8*2048*384 = 6,291,456 floats
        ((float4*)h)[t] = z;
    if (t < (size_t)POOLED_N / 4)               // pooled: 4,194,304 floats
        ((float4*)pooled)[t] = z;
    if (t == 0) { out_scalars[0] = 0.f; out_scalars[1] = 0.f; *nf = 0; }
}

// ---------------------------------------------------------------------------
// Convert w1 (Ch,D,K) -> bpack[c][k'=kk*1024+d] fp16, c padded to 384.
// ---------------------------------------------------------------------------
__global__ __launch_bounds__(256) void convert_w1_kernel(
        const float* __restrict__ w1, _Float16* __restrict__ bpack) {
    int idx = blockIdx.x * 256 + threadIdx.x;   // < 384*3072
    int c = idx / KDIM;
    int kp = idx - c * KDIM;
    int kk = kp >> 10, d = kp & 1023;
    float v = (c < CH) ? w1[((size_t)c * 1024 + d) * 3 + kk] : 0.0f;
    bpack[idx] = (_Float16)v;
}

// ---------------------------------------------------------------------------
// fp16 MFMA conv GEMM, K-split by conv tap (kk=0,1,2; each K=1024).
// Block: tile 128 l x 96 c, BK=64, 16 steps, 4 waves, wave-tile 64x48.
// Grid (12,16,8) = 1536 blocks; 28KB LDS single-buffer -> 5 blocks/CU,
// 20 waves/CU. Blocks atomicAdd raw (pre-relu) partial sums into
// h[b][l][CP] fp32 (zeroed by convert_hidden).
// LDS in fragment order -> conflict-free ds_read_b128.
// ---------------------------------------------------------------------------
__global__ __launch_bounds__(256, 4) void conv_mfma_kernel(
        const _Float16* __restrict__ hid16, const _Float16* __restrict__ bpack,
        float* __restrict__ h) {
    const int xt = blockIdx.x;           // kk*4 + nt
    const int kk = xt >> 2, nt = xt & 3;
    const int mt = blockIdx.y;           // 0..15
    const int b  = blockIdx.z;
    const int l0 = mt * 128;
    const int n0 = nt * 96;
    const int tid = threadIdx.x;
    const int wave = tid >> 6, lane = tid & 63;
    const int wm = wave & 1, wn = wave >> 1;
    const int quad = lane >> 4, l16 = lane & 15;

    __shared__ __align__(16) char lds[28672];   // A 16K (1024 ent) + B 12K (768 ent)

    // A[l][kk*1024 + d] = hid_flat[(l+kk)*1024 + d]
    const _Float16* hb = hid16 + (size_t)b * L_SZ * D_SZ + (size_t)kk * 1024;

    // A staging: entry f = kc*512 + mf*64 + le ; l = l0+mf*16+(le&15),
    // k = kc*32 + (le>>4)*8. 4 entries per thread.
    const _Float16* pa[4];
    #pragma unroll
    for (int p = 0; p < 4; ++p) {
        int f = p * 256 + tid;
        int kc = f >> 9, mf = (f >> 6) & 7, le = f & 63;
        int l = l0 + mf * 16 + (le & 15);
        if (l > LCONV - 1) l = LCONV - 1;
        pa[p] = hb + (size_t)l * 1024 + kc * 32 + (le >> 4) * 8;
    }
    // B staging: entry f = kc*384 + nfr*64 + le ; n = n0+nfr*16+(le&15)
    const _Float16* pb[3];
    #pragma unroll
    for (int p = 0; p < 3; ++p) {
        int f = p * 256 + tid;
        int kc = (f >= 384) ? 1 : 0;
        int e = f - kc * 384;
        int nfr = e >> 6, le = e & 63;
        pb[p] = bpack + (size_t)(n0 + nfr * 16 + (le & 15)) * KDIM
              + kk * 1024 + kc * 32 + (le >> 4) * 8;
    }

    f32x4 acc[4][3] = {};

    for (int s = 0; s < 16; ++s) {
        #pragma unroll
        for (int p = 0; p < 4; ++p)
            gl_lds16(pa[p], lds + (p * 256 + wave * 64) * 16);
        #pragma unroll
        for (int p = 0; p < 3; ++p)
            gl_lds16(pb[p], lds + 16384 + (p * 256 + wave * 64) * 16);
        #pragma unroll
        for (int p = 0; p < 4; ++p) pa[p] += 64;
        #pragma unroll
        for (int p = 0; p < 3; ++p) pb[p] += 64;
        __syncthreads();
        #pragma unroll
        for (int kc = 0; kc < 2; ++kc) {
            f16x8 a[4], bb[3];
            #pragma unroll
            for (int ii = 0; ii < 4; ++ii)
                a[ii] = *(const f16x8*)(lds + ((kc * 512 + (wm * 4 + ii) * 64 + lane)) * 16);
            #pragma unroll
            for (int jj = 0; jj < 3; ++jj)
                bb[jj] = *(const f16x8*)(lds + 16384 + ((kc * 384 + (wn * 3 + jj) * 64 + lane)) * 16);
            #pragma unroll
            for (int ii = 0; ii < 4; ++ii)
                #pragma unroll
                for (int jj = 0; jj < 3; ++jj)
                    acc[ii][jj] = __builtin_amdgcn_mfma_f32_16x16x32_f16(
                        a[ii], bb[jj], acc[ii][jj], 0, 0, 0);
        }
        __syncthreads();
    }

    // epilogue: atomic-accumulate raw partial sums into h
    #pragma unroll
    for (int ii = 0; ii < 4; ++ii) {
        #pragma unroll
        for (int r = 0; r < 4; ++r) {
            int l = l0 + wm * 64 + ii * 16 + quad * 4 + r;
            if (l < LCONV) {
                float* dst = h + ((size_t)b * L_SZ + l) * CP + n0 + wn * 48 + l16;
                #pragma unroll
                for (int jj = 0; jj < 3; ++jj)
                    atomicAdd(dst + jj * 16, acc[ii][jj][r]);
            }
        }
    }
}

// ---------------------------------------------------------------------------
// logit = sum_c relu(h[c]+b1[c])*w2[c] + b2. One wave per l.
// Flags |logit| < 0.25 (~9 sigma of fp16-GEMM logit error) into fixlist and
// writes b2 there instead (fixup_b adds the exact channel sums).
// ---------------------------------------------------------------------------
__global__ __launch_bounds__(256) void logit_reduce_kernel(
        const float* __restrict__ h, const float* __restrict__ b1,
        const float* __restrict__ w2, const float* __restrict__ b2,
        float* __restrict__ logits, int* __restrict__ fixlist,
        int* __restrict__ nf) {
    const int b = blockIdx.y;
    const int l = blockIdx.x * 4 + (threadIdx.x >> 6);
    const int lane = threadIdx.x & 63;
    if (l >= LCONV) return;
    const float* hr = h + ((size_t)b * L_SZ + l) * CP;
    float s = 0.f;
    #pragma unroll
    for (int t = 0; t < 6; ++t) {
        int c = lane + 64 * t;
        if (c < CH) {
            float v = hr[c] + b1[c];
            if (v > 0.f) s += v * w2[c];
        }
    }
    #pragma unroll
    for (int off = 32; off > 0; off >>= 1) s += __shfl_down(s, off);
    if (lane == 0) {
        float lg = s + b2[0];
        if (fabsf(lg) < 0.25f) {
            int k = atomicAdd(nf, 1);
            if (k < NFCAP) { fixlist[k] = (b << 16) | l; lg = b2[0]; }
        }
        logits[b * LCONV + l] = lg;
    }
}

// ---------------------------------------------------------------------------
// Exact fp32 fixup phase B: grid (8 slices, NFCAP). Block (slice,j) adds the
// exact relu-channel sums for channels [slice*43, slice*43+43) of flagged
// position j onto the b2-initialized logit. Inactive blocks exit instantly.
// ---------------------------------------------------------------------------
__global__ __launch_bounds__(256) void fixup_b_kernel(
        const float* __restrict__ hidden, const float* __restrict__ w1,
        const float* __restrict__ b1, const float* __restrict__ w2,
        const int* __restrict__ fixlist, const int* __restrict__ nf,
        float* __restrict__ logits) {
    const int j = blockIdx.y;
    int n = *nf; if (n > NFCAP) n = NFCAP;
    if (j >= n) return;
    const int slice = blockIdx.x;
    const int code = fixlist[j];
    const int b = code >> 16, l = code & 0xffff;

    __shared__ __align__(16) float hrow[3072];   // rows l..l+2 of hidden
    const float* src = hidden + ((size_t)b * L_SZ + l) * 1024;
    for (int t = threadIdx.x; t < 768; t += 256)
        ((float4*)hrow)[t] = ((const float4*)src)[t];
    __syncthreads();

    const int wave = threadIdx.x >> 6, lane = threadIdx.x & 63;
    int c0 = slice * 43, cend = c0 + 43;
    if (cend > CH) cend = CH;
    float wsum = 0.f;
    for (int c = c0 + wave; c < cend; c += 4) {
        const float* wr = w1 + (size_t)c * 3072;
        float dot = 0.f;
        // j = lane + 64*t ; w1 index j = d*3+kk -> hrow index kk*1024+d
        int jm = lane % 3, jd = lane / 3;
        #pragma unroll 8
        for (int t = 0; t < 48; ++t) {
            dot += wr[lane + 64 * t] * hrow[jm * 1024 + jd];
            jm += 1; jd += 21;
            if (jm == 3) { jm = 0; jd += 1; }
        }
        #pragma unroll
        for (int off = 32; off > 0; off >>= 1) dot += __shfl_down(dot, off);
        if (lane == 0) {
            float v = dot + b1[c];
            if (v > 0.f) wsum += v * w2[c];
        }
    }
    if (lane == 0) atomicAdd(&logits[b * LCONV + l], wsum);
}

// ---------------------------------------------------------------------------
// Boundary scan: hard bits, segment starts, per-token segment ids,
// short_mask, scalar outputs.
// ---------------------------------------------------------------------------
__global__ void boundary_scan_kernel(const float* __restrict__ logits,
                                     const float* __restrict__ amask,
                                     int* __restrict__ segstart,
                                     int* __restrict__ segid,
                                     float* __restrict__ out_nb,
                                     float* __restrict__ out_tp,
                                     float* __restrict__ short_mask) {
    const int b = blockIdx.x, tid = threadIdx.x;
    __shared__ int sdata[256];
    __shared__ int s_len, s_total;

    int cnt = 0;
    #pragma unroll
    for (int j = 0; j < 8; ++j) {
        int l = tid * 8 + j;
        cnt += (amask[b * L_SZ + l] > 0.5f) ? 1 : 0;
    }
    sdata[tid] = cnt; __syncthreads();
    for (int off = 128; off > 0; off >>= 1) {
        if (tid < off) sdata[tid] += sdata[tid + off];
        __syncthreads();
    }
    if (tid == 0) s_len = sdata[0];
    __syncthreads();
    const int len = s_len;

    int bits[8]; int tsum = 0;
    #pragma unroll
    for (int j = 0; j < 8; ++j) {
        int l = tid * 8 + j;
        int hh = 0;
        if (l >= 2 && l < len) hh = (logits[b * LCONV + (l - 2)] > 0.0f) ? 1 : 0;
        if (len < L_SZ && l == len - 1) hh = 1;
        bits[j] = hh; tsum += hh;
    }
    __syncthreads();
    sdata[tid] = tsum; __syncthreads();
    for (int off = 1; off < 256; off <<= 1) {
        int v = (tid >= off) ? sdata[tid - off] : 0;
        __syncthreads();
        sdata[tid] += v;
        __syncthreads();
    }
    const int texcl = sdata[tid] - tsum;
    if (tid == 255) s_total = sdata[255];
    __syncthreads();
    const int total = s_total;

    for (int s = tid; s <= NSEG; s += 256)
        segstart[b * (NSEG + 1) + s] = (s == 0) ? 0 : len;
    __syncthreads();
    int run = texcl;
    #pragma unroll
    for (int j = 0; j < 8; ++j) {
        int l = tid * 8 + j;
        int sv = -1;
        if (l < len && run < NSEG) sv = run;
        segid[b * L_SZ + l] = sv;
        if (bits[j]) {
            if (run + 1 <= NSEG) segstart[b * (NSEG + 1) + run + 1] = l + 1;
            run++;
        }
    }

    if (tid == 0) {
        atomicAdd(out_nb, (float)total);
        atomicAdd(out_tp, (float)len);
    }
    for (int s = tid; s < NSEG; s += 256)
        short_mask[b * NSEG + s] = (s < total) ? 1.0f : 0.0f;
}

// ---------------------------------------------------------------------------
// Pool accumulate: 16-token chunks, thread = 4 d over the chunk, atomic flush
// per segment run. Grid (128,8) x 256 threads.
// ---------------------------------------------------------------------------
__global__ __launch_bounds__(256) void pool_accum_kernel(
        const float* __restrict__ hidden, const int* __restrict__ segid,
        float* __restrict__ pooled) {
    const int chunk = blockIdx.x, b = blockIdx.y;
    const int tid = threadIdx.x;
    const int d0 = tid * 4;
    const int lbase = chunk * 16;
    const float* hb = hidden + (size_t)b * L_SZ * D_SZ + d0;
    const int* sg = segid + b * L_SZ + lbase;
    float4 acc = make_float4(0.f, 0.f, 0.f, 0.f);
    int cur = -1;
    #pragma unroll
    for (int t = 0; t < 16; ++t) {
        int sid = sg[t];
        if (sid != cur) {
            if (cur >= 0) {
                float* dst = pooled + ((size_t)(b * NSEG + cur)) * D_SZ + d0;
                atomicAdd(dst + 0, acc.x); atomicAdd(dst + 1, acc.y);
                atomicAdd(dst + 2, acc.z); atomicAdd(dst + 3, acc.w);
            }
            acc = make_float4(0.f, 0.f, 0.f, 0.f);
            cur = sid;
        }
        if (sid >= 0) {
            float4 v = *(const float4*)(hb + (size_t)(lbase + t) * D_SZ);
            acc.x += v.x; acc.y += v.y; acc.z += v.z; acc.w += v.w;
        }
    }
    if (cur >= 0) {
        float* dst = pooled + ((size_t)(b * NSEG + cur)) * D_SZ + d0;
        atomicAdd(dst + 0, acc.x); atomicAdd(dst + 1, acc.y);
        atomicAdd(dst + 2, acc.z); atomicAdd(dst + 3, acc.w);
    }
}

// ---------------------------------------------------------------------------
// Pool finalize: divide by count, add sinusoidal PE.
// ---------------------------------------------------------------------------
__global__ __launch_bounds__(256) void pool_final_kernel(
        float* __restrict__ pooled, const int* __restrict__ segstart) {
    const int s = blockIdx.x, b = blockIdx.y, tid = threadIdx.x;
    const int l0 = segstart[b * (NSEG + 1) + s];
    const int l1 = segstart[b * (NSEG + 1) + s + 1];
    const float inv = 1.0f / ((float)(l1 - l0) + 1e-9f);
    const int d0 = tid * 4;
    size_t o = ((size_t)(b * NSEG + s)) * D_SZ + d0;
    float4 v = *(float4*)(pooled + o);
    const float ce = -9.210340371976184f / 512.0f;
    const int i = d0 >> 1;
    const float a0 = (float)s * expf(ce * (float)i);
    const float a1 = (float)s * expf(ce * (float)(i + 1));
    float4 out;
    out.x = v.x * inv + sinf(a0);
    out.y = v.y * inv + cosf(a0);
    out.z = v.z * inv + sinf(a1);
    out.w = v.w * inv + cosf(a1);
    *(float4*)(pooled + o) = out;
}

// ---------------------------------------------------------------------------
extern "C" void kernel_launch(void* const* d_in, const int* in_sizes, int n_in,
                              void* d_out, int out_size, void* d_ws, size_t ws_size,
                              hipStream_t stream) {
    const float* hidden = (const float*)d_in[0];
    const float* amask  = (const float*)d_in[1];
    const float* w1     = (const float*)d_in[2];
    const float* b1     = (const float*)d_in[3];
    const float* w2     = (const float*)d_in[4];
    const float* b2     = (const float*)d_in[5];

    float* out    = (float*)d_out;
    float* pooled = out;
    float* nb     = out + POOLED_N;
    float* smask  = out + POOLED_N + 2;

    const size_t HID_E = (size_t)B_SZ * L_SZ * D_SZ;           // 16,777,216
    const size_t OFF_HID16    = 0;
    const size_t OFF_BPACK    = OFF_HID16 + HID_E * 2;                  // 32 MB
    const size_t OFF_H        = OFF_BPACK + (size_t)CP * KDIM * 2;      // +2.25 MB
    const size_t OFF_LOGITS   = OFF_H + (size_t)B_SZ * L_SZ * CP * 4;   // +25.2 MB
    const size_t OFF_SEGSTART = OFF_LOGITS + (size_t)B_SZ * LCONV * 4;
    const size_t OFF_SEGID    = OFF_SEGSTART + (size_t)B_SZ * (NSEG + 1) * 4;
    const size_t OFF_FIX      = OFF_SEGID + (size_t)B_SZ * L_SZ * 4;

    _Float16* hid16  = (_Float16*)((char*)d_ws + OFF_HID16);
    _Float16* bpack  = (_Float16*)((char*)d_ws + OFF_BPACK);
    float*    h      = (float*)((char*)d_ws + OFF_H);
    float*    logits = (float*)((char*)d_ws + OFF_LOGITS);
    int*      segst  = (int*)((char*)d_ws + OFF_SEGSTART);
    int*      segid  = (int*)((char*)d_ws + OFF_SEGID);
    int*      fixlist= (int*)((char*)d_ws + OFF_FIX);
    int*      nf     = fixlist + NFCAP;

    convert_hidden_kernel<<<8192, 256, 0, stream>>>(hidden, hid16, h, pooled, nb, nf);
    convert_w1_kernel<<<(CP * KDIM) / 256, 256, 0, stream>>>(w1, bpack);
    conv_mfma_kernel<<<dim3(12, 16, B_SZ), 256, 0, stream>>>(hid16, bpack, h);
    logit_reduce_kernel<<<dim3(512, B_SZ), 256, 0, stream>>>(h, b1, w2, b2, logits, fixlist, nf);
    fixup_b_kernel<<<dim3(8, NFCAP), 256, 0, stream>>>(hidden, w1, b1, w2, fixlist, nf, logits);
    boundary_scan_kernel<<<B_SZ, 256, 0, stream>>>(logits, amask, segst, segid, nb, nb + 1, smask);
    pool_accum_kernel<<<dim3(128, B_SZ), 256, 0, stream>>>(hidden, segid, pooled);
    pool_final_kernel<<<dim3(NSEG, B_SZ), 256, 0, stream>>>(pooled, segst);
}